// Round 6
// baseline (589.752 us; speedup 1.0000x reference)
//
#include <hip/hip_runtime.h>
#include <hip/hip_fp16.h>

// NodeGCN: 3x GCNConv(H=20) + BN/ReLU + final linear, N=100K, E=3.2M.
// R13: edge-parallel SEGMENTED-REDUCTION agg (per-bucket), scatter reverted.
//  - R12 post-mortem: scatter GBS 128 regressed (occupancy 5%, latency-bound;
//    WRITE_SIZE did drop 94->48MB as predicted) -> revert GB=512.
//    agg depth-3 was ~neutral: per-node walk is a DEPENDENT chain; structural.
//  - New agg: one block (512thr) per 128-node bucket. se is dst-sorted, so
//    each lane takes a contiguous ~9-edge chunk: gathers are INDEPENDENT
//    (MLP hides latency), accumulate in 20 regs while dst unchanged, flush
//    20 LDS atomicAdds only at run boundaries (~6M total vs R9's 64M).
//    Chunk size rounded odd -> sse ds_read conflicts 32-way -> 4-way.
//  - se keeps (src | local<<20) payload (finalize no longer masks local out).
//  - Epilogue = R9's verified per-bucket form (self-loop+dinv+bias+ReLU,
//    BN stats MODE0 / fused final linear MODE1).

#define HD 20
#define EPS 1e-5f
#define BSH 7            // 128 nodes per bucket
#define NBMAX 1024
#define CAP 5632         // finalize: max edges per bucket staged in LDS
#define CAPE 4800        // agg: max edges per bucket staged in LDS (mean 4092)

typedef float __attribute__((ext_vector_type(4))) f4v;

__device__ __forceinline__ float4 ntld4(const float* p) {
    f4v v = __builtin_nontemporal_load((const f4v*)p);
    return make_float4(v.x, v.y, v.z, v.w);
}

__global__ __launch_bounds__(1024)
void init_kernel(int* bcnt, float* stats, float* zero20, int nbv) {
    int t = threadIdx.x;
    if (t < nbv) bcnt[t] = 0;
    if (t < 80) stats[t] = 0.0f;
    if (t < HD) zero20[t] = 0.0f;
}

__global__ __launch_bounds__(256)
void bucket_hist_kernel(const int* __restrict__ dst, int* __restrict__ bcnt,
                        int E, int chunk, int nbv) {
    __shared__ int lh[NBMAX];
    for (int i = threadIdx.x; i < nbv; i += 256) lh[i] = 0;
    __syncthreads();
    int s = blockIdx.x * chunk;
    int e = s + chunk; if (e > E) e = E;
    for (int j = s + threadIdx.x; j < e; j += 256)
        atomicAdd(&lh[dst[j] >> BSH], 1);
    __syncthreads();
    for (int i = threadIdx.x; i < nbv; i += 256)
        if (lh[i]) atomicAdd(&bcnt[i], lh[i]);
}

// single block: exclusive scan bcnt[0..nbv) -> bstart, init bcur, row_start[N]=E
__global__ __launch_bounds__(1024)
void bucket_scan_kernel(const int* __restrict__ bcnt, int* __restrict__ bstart,
                        int* __restrict__ bcur, int* __restrict__ row_start,
                        int n, int E, int nbv) {
    __shared__ int s[1024];
    int t = threadIdx.x;
    int v = (t < nbv) ? bcnt[t] : 0;
    s[t] = v;
    __syncthreads();
    for (int off = 1; off < 1024; off <<= 1) {
        int u = (t >= off) ? s[t - off] : 0;
        __syncthreads();
        s[t] += u;
        __syncthreads();
    }
    if (t < nbv) { int st = s[t] - v; bstart[t] = st; bcur[t] = st; }
    if (t == 0) { bstart[nbv] = E; row_start[n] = E; }
}

// scatter edges into bucket-grouped tmp; payload packed (src | local<<20, ew)
__global__ __launch_bounds__(256)
void scatter_kernel(const int* __restrict__ src, const int* __restrict__ dst,
                    const float* __restrict__ ew, int* __restrict__ bcur,
                    int2* __restrict__ tmp, int E, int chunk, int nbv) {
    __shared__ int lh[NBMAX];
    __shared__ int lbase[NBMAX];
    for (int i = threadIdx.x; i < nbv; i += 256) lh[i] = 0;
    __syncthreads();
    int s = blockIdx.x * chunk;
    int e = s + chunk; if (e > E) e = E;
    for (int j = s + threadIdx.x; j < e; j += 256)
        atomicAdd(&lh[dst[j] >> BSH], 1);
    __syncthreads();
    for (int i = threadIdx.x; i < nbv; i += 256) {
        int c = lh[i];
        lbase[i] = c ? atomicAdd(&bcur[i], c) : 0;
        lh[i] = 0;                         // reuse as local cursor
    }
    __syncthreads();
    for (int j = s + threadIdx.x; j < e; j += 256) {
        int d = dst[j];
        int b = d >> BSH;
        int pos = atomicAdd(&lh[b], 1);
        tmp[lbase[b] + pos] = make_int2(src[j] | ((d & ((1 << BSH) - 1)) << 20),
                                        __float_as_int(ew[j]));
    }
}

// one block per bucket: in-LDS counting sort by local dst; emit sorted se
// (KEEPS src|local<<20 packing) + row_start + dinv
__global__ __launch_bounds__(256)
void finalize_kernel(const int2* __restrict__ tmp, const int* __restrict__ bstart,
                     int2* __restrict__ se, int* __restrict__ row_start,
                     float* __restrict__ dinv, int n) {
    __shared__ int hist[128];
    __shared__ float degs[128];
    __shared__ int off[128];
    __shared__ int cur[128];
    __shared__ int2 stage[CAP];
    int b = blockIdx.x;
    int s0 = bstart[b], s1 = bstart[b + 1];
    int cnt = s1 - s0;
    int t = threadIdx.x;
    if (t < 128) { hist[t] = 0; degs[t] = 0.0f; cur[t] = 0; }
    __syncthreads();
    for (int j = s0 + t; j < s1; j += 256) {
        int2 r = tmp[j];
        int l = r.x >> 20;
        atomicAdd(&hist[l], 1);
        atomicAdd(&degs[l], __int_as_float(r.y));
    }
    __syncthreads();
    if (t < 128) off[t] = hist[t];
    __syncthreads();
    for (int o = 1; o < 128; o <<= 1) {           // inclusive scan
        int u = (t < 128 && t >= o) ? off[t - o] : 0;
        __syncthreads();
        if (t < 128) off[t] += u;
        __syncthreads();
    }
    if (t < 128) {
        int node = (b << BSH) + t;
        if (node < n) {
            row_start[node] = s0 + off[t] - hist[t];   // exclusive
            dinv[node] = rsqrtf(1.0f + degs[t]);
        }
    }
    __syncthreads();
    if (cnt <= CAP) {
        for (int j = s0 + t; j < s1; j += 256) {
            int2 r = tmp[j];
            int l = r.x >> 20;
            int p = (off[l] - hist[l]) + atomicAdd(&cur[l], 1);
            stage[p] = r;                       // keep local bits
        }
        __syncthreads();
        for (int k = t; k < cnt; k += 256) se[s0 + k] = stage[k];
    } else {   // overflow fallback (correctness net; not taken for this input)
        for (int j = s0 + t; j < s1; j += 256) {
            int2 r = tmp[j];
            int l = r.x >> 20;
            int p = (off[l] - hist[l]) + atomicAdd(&cur[l], 1);
            se[s0 + p] = r;
        }
    }
}

// hs[n,20](fp16) = ((in[n,FIN] @ W[FIN,20]) + cvec) * dinv[n]
template<int FIN, int NPB>
__global__ __launch_bounds__(256)
void gemm_kernel(const float* __restrict__ in, const float* __restrict__ W,
                 const float* __restrict__ cvec, const float* __restrict__ dinv,
                 __half* __restrict__ hs, int n) {
    __shared__ float sWt[HD][FIN + 4];
    __shared__ float sIn[NPB][FIN + 4];
    __shared__ float sC[HD];
    for (int i = threadIdx.x; i < FIN * HD; i += 256) {
        int k = i / HD, f = i % HD;           // W row-major [k][f]
        sWt[f][k] = W[i];
    }
    if (threadIdx.x < HD) sC[threadIdx.x] = cvec[threadIdx.x];
    int base = blockIdx.x * NPB;
    int nb = n - base; if (nb > NPB) nb = NPB;
    int lim = n * FIN;
    const int Q = FIN / 4;
    for (int i = threadIdx.x; i < NPB * Q; i += 256) {
        int row = i / Q, c = (i % Q) * 4;
        int g = (base + row) * FIN + c;
        *(float4*)&sIn[row][c] = (g < lim) ? ntld4(&in[g])
                                           : make_float4(0.f, 0.f, 0.f, 0.f);
    }
    __syncthreads();
    for (int idx = threadIdx.x; idx < NPB * HD; idx += 256) {
        int nl = idx / HD, f = idx % HD;
        float4 a = make_float4(0.f, 0.f, 0.f, 0.f);
        #pragma unroll 4
        for (int k = 0; k < FIN; k += 4) {
            float4 x4 = *(const float4*)&sIn[nl][k];
            float4 w4 = *(const float4*)&sWt[f][k];
            a.x = fmaf(x4.x, w4.x, a.x);
            a.y = fmaf(x4.y, w4.y, a.y);
            a.z = fmaf(x4.z, w4.z, a.z);
            a.w = fmaf(x4.w, w4.w, a.w);
        }
        if (nl < nb)
            hs[(size_t)(base + nl) * HD + f] = __float2half_rn(
                (((a.x + a.y) + (a.z + a.w)) + sC[f]) * dinv[base + nl]);
    }
}

__device__ __forceinline__ float4 h4f2(uint2 u) {
    float2 f0 = __half22float2(*reinterpret_cast<const __half2*>(&u.x));
    float2 f1 = __half22float2(*reinterpret_cast<const __half2*>(&u.y));
    return make_float4(f0.x, f0.y, f1.x, f1.y);
}

// 40B row gather: dwordx4 + dwordx4 + dwordx2 (dword alignment suffices).
#define ROWLD(Q0, Q1, Q2, SRC) { \
    const char* rp_ = (const char*)hsb + (size_t)(SRC) * 40; \
    Q0 = *(const uint4*)rp_; \
    Q1 = *(const uint4*)(rp_ + 16); \
    Q2 = *(const uint2*)(rp_ + 32); }

#define ZERO20(A) { _Pragma("unroll") for (int f_ = 0; f_ < HD; ++f_) A[f_] = 0.0f; }

#define FLUSH20(LOC, A) { float* ap_ = &acc[LOC][0]; \
    _Pragma("unroll") for (int f_ = 0; f_ < HD; ++f_) atomicAdd(ap_ + f_, A[f_]); }

#define ACCUM20(A, C0, C1, C2, W) { \
    float4 v0_ = h4f2(make_uint2(C0.x, C0.y)); \
    float4 v1_ = h4f2(make_uint2(C0.z, C0.w)); \
    float4 v2_ = h4f2(make_uint2(C1.x, C1.y)); \
    float4 v3_ = h4f2(make_uint2(C1.z, C1.w)); \
    float4 v4_ = h4f2(C2); \
    A[0]  = fmaf(v0_.x, W, A[0]);  A[1]  = fmaf(v0_.y, W, A[1]); \
    A[2]  = fmaf(v0_.z, W, A[2]);  A[3]  = fmaf(v0_.w, W, A[3]); \
    A[4]  = fmaf(v1_.x, W, A[4]);  A[5]  = fmaf(v1_.y, W, A[5]); \
    A[6]  = fmaf(v1_.z, W, A[6]);  A[7]  = fmaf(v1_.w, W, A[7]); \
    A[8]  = fmaf(v2_.x, W, A[8]);  A[9]  = fmaf(v2_.y, W, A[9]); \
    A[10] = fmaf(v2_.z, W, A[10]); A[11] = fmaf(v2_.w, W, A[11]); \
    A[12] = fmaf(v3_.x, W, A[12]); A[13] = fmaf(v3_.y, W, A[13]); \
    A[14] = fmaf(v3_.z, W, A[14]); A[15] = fmaf(v3_.w, W, A[15]); \
    A[16] = fmaf(v4_.x, W, A[16]); A[17] = fmaf(v4_.y, W, A[17]); \
    A[18] = fmaf(v4_.z, W, A[18]); A[19] = fmaf(v4_.w, W, A[19]); }

// Segmented per-lane run loop, depth-2 pipeline (next row in flight).
#define SEG_LOOP(EDGEAT)                                                     \
    {                                                                        \
        int k = b0;                                                          \
        int2 e = EDGEAT(k);                                                  \
        uint4 c0, c1; uint2 c2; ROWLD(c0, c1, c2, e.x & 0xFFFFF)             \
        while (true) {                                                       \
            int kn = k + 1;                                                  \
            bool more = kn < b1;                                             \
            int2 en = EDGEAT(more ? kn : k);                                 \
            uint4 n0, n1; uint2 n2; ROWLD(n0, n1, n2, en.x & 0xFFFFF)        \
            int loc = e.x >> 20;                                             \
            if (loc != curd) {                                               \
                if (curd >= 0) FLUSH20(curd, racc)                           \
                curd = loc;                                                  \
                ZERO20(racc)                                                 \
            }                                                                \
            float w = __int_as_float(e.y);                                   \
            ACCUM20(racc, c0, c1, c2, w)                                     \
            if (!more) break;                                                \
            k = kn; e = en;                                                  \
            c0 = n0; c1 = n1; c2 = n2;                                       \
        }                                                                    \
        if (curd >= 0) FLUSH20(curd, racc)                                   \
    }

#define EDGE_LDS(kk) sse[(kk)]
#define EDGE_GBL(kk) se[s0 + (kk)]

// MODE 0: layers 1/2 — write o rows + BN stats.  MODE 1: layer 3 + final linear.
// One block (512 thr) per 128-node bucket; edge-parallel segmented reduction.
template<int MODE>
__global__ __launch_bounds__(512)
void agg_kernel(const __half* __restrict__ hsb, const float* __restrict__ dinv,
                const int2* __restrict__ se, const int* __restrict__ bstart,
                const float* __restrict__ bias, float* __restrict__ out,
                float* __restrict__ stat_sum, float* __restrict__ stat_sq,
                const float* __restrict__ o1, const float* __restrict__ o2,
                const float* __restrict__ Wlp, const float* __restrict__ blp,
                int n) {
    __shared__ int2 sse[CAPE];          // 38.4 KB
    __shared__ float acc[128][21];      // 10.75 KB, stride 21 -> bank spread
    __shared__ float sbias[HD];
    __shared__ float sW[600];
    __shared__ float sb[10];
    int t = threadIdx.x, b = blockIdx.x;
    int s0 = bstart[b], s1 = bstart[b + 1];
    int span = s1 - s0;
    bool ok = (span <= CAPE);
    for (int i = t; i < 128 * 21; i += 512) ((float*)acc)[i] = 0.0f;
    if (t < HD) sbias[t] = bias[t];
    if (MODE == 1) {
        for (int i = t; i < 600; i += 512) sW[i] = Wlp[i];
        if (t < 10) sb[t] = blp[t];
    }
    if (ok) {
        for (int k = t; k < span; k += 512) {
            long long v = __builtin_nontemporal_load(
                (const long long*)(se + s0 + k));
            sse[k] = *(const int2*)&v;
        }
    }
    __syncthreads();

    // per-lane contiguous chunk; c odd -> 4-way (not 32-way) sse bank alias
    int c = ((span + 511) >> 9) | 1;
    int b0 = t * c;
    int b1 = b0 + c; if (b1 > span) b1 = span;
    if (b0 < b1) {
        float racc[HD];
        int curd = -1;
        if (ok) { SEG_LOOP(EDGE_LDS) }
        else    { SEG_LOOP(EDGE_GBL) }
    }
    __syncthreads();

    // ---- epilogue: self-loop + dinv + bias + relu, then MODE-specific ----
    if (t < 128) {
        int i = (b << BSH) + t;
        if (i < n) {
            float di = dinv[i];
            uint4 q0, q1; uint2 q2;
            ROWLD(q0, q1, q2, i)
            float sf[HD];
            *(float4*)&sf[0]  = h4f2(make_uint2(q0.x, q0.y));
            *(float4*)&sf[4]  = h4f2(make_uint2(q0.z, q0.w));
            *(float4*)&sf[8]  = h4f2(make_uint2(q1.x, q1.y));
            *(float4*)&sf[12] = h4f2(make_uint2(q1.z, q1.w));
            *(float4*)&sf[16] = h4f2(q2);
            float va[HD];
            #pragma unroll
            for (int f = 0; f < HD; ++f)
                va[f] = fmaxf((acc[t][f] + sf[f]) * di + sbias[f], 0.0f);
            if (MODE == 0) {
                float4* op = (float4*)(out + (size_t)i * HD);
                #pragma unroll
                for (int q = 0; q < 5; ++q)
                    op[q] = make_float4(va[4*q], va[4*q+1], va[4*q+2], va[4*q+3]);
                #pragma unroll
                for (int f = 0; f < HD; ++f) acc[t][f] = va[f];  // for stats
            } else {
                float r1[HD], r2[HD];
                const float4* p1 = (const float4*)(o1 + (size_t)i * HD);
                const float4* p2 = (const float4*)(o2 + (size_t)i * HD);
                #pragma unroll
                for (int q = 0; q < 5; ++q) {
                    *(float4*)&r1[4*q] = p1[q];
                    *(float4*)&r2[4*q] = p2[q];
                }
                #pragma unroll
                for (int cc = 0; cc < 10; ++cc) {
                    float s = sb[cc];
                    #pragma unroll
                    for (int k = 0; k < HD; ++k) s = fmaf(r1[k], sW[k * 10 + cc], s);
                    #pragma unroll
                    for (int k = 0; k < HD; ++k) s = fmaf(r2[k], sW[(HD + k) * 10 + cc], s);
                    #pragma unroll
                    for (int k = 0; k < HD; ++k) s = fmaf(va[k], sW[(2 * HD + k) * 10 + cc], s);
                    out[(size_t)i * 10 + cc] = s;
                }
            }
        }
        // i >= n: acc row stays zero -> contributes 0 to stats
    }
    if (MODE == 0) {
        __syncthreads();
        if (t < HD) {
            float s = 0.0f, q = 0.0f;
            #pragma unroll 8
            for (int nl = 0; nl < 128; ++nl) {
                float v = acc[nl][t];
                s += v; q += v * v;
            }
            atomicAdd(&stat_sum[t], s);
            atomicAdd(&stat_sq[t], q);
        }
    }
}

// BN finalize + fold into next conv: scsh_out = (scale,shift);
// Wp[k][f] = sc[k]*W[k][f]; cvec[f] = sum_k sh[k]*W[k][f]
__global__ __launch_bounds__(512)
void bn_adjust_kernel(const float* __restrict__ sum, const float* __restrict__ sq,
                      const float* __restrict__ g, const float* __restrict__ be,
                      const float* __restrict__ W, float* __restrict__ scsh_out,
                      float* __restrict__ Wp, float* __restrict__ cvec, int n) {
    __shared__ float ssc[HD], ssh[HD];
    int t = threadIdx.x;
    if (t < HD) {
        float inv_n = 1.0f / (float)n;
        float m = sum[t] * inv_n;
        float var = sq[t] * inv_n - m * m;
        float sc = g[t] * rsqrtf(var + EPS);
        float sh = be[t] - m * sc;
        ssc[t] = sc; ssh[t] = sh;
        scsh_out[t] = sc; scsh_out[HD + t] = sh;
    }
    __syncthreads();
    if (t < HD * HD) Wp[t] = ssc[t / HD] * W[t];
    if (t < HD) {
        float acc = 0.0f;
        #pragma unroll
        for (int k = 0; k < HD; ++k) acc = fmaf(ssh[k], W[k * HD + t], acc);
        cvec[t] = acc;
    }
}

// second BN: same as above + build Wlp/blp for the fused final.
// Wlp rows: 0..19 *= sc1, 20..39 *= sc2, 40..59 UNSCALED (o3 block).
__global__ __launch_bounds__(640)
void bn_adjust2_kernel(const float* __restrict__ sum, const float* __restrict__ sq,
                       const float* __restrict__ g, const float* __restrict__ be,
                       const float* __restrict__ W, float* __restrict__ scsh_out,
                       float* __restrict__ Wp, float* __restrict__ cvec,
                       const float* __restrict__ Wl, const float* __restrict__ bl,
                       const float* __restrict__ scsh1,
                       float* __restrict__ Wlp, float* __restrict__ blp, int n) {
    __shared__ float ssc[HD], ssh[HD];
    int t = threadIdx.x;
    if (t < HD) {
        float inv_n = 1.0f / (float)n;
        float m = sum[t] * inv_n;
        float var = sq[t] * inv_n - m * m;
        float sc = g[t] * rsqrtf(var + EPS);
        float sh = be[t] - m * sc;
        ssc[t] = sc; ssh[t] = sh;
        scsh_out[t] = sc; scsh_out[HD + t] = sh;
    }
    __syncthreads();
    if (t < HD * HD) Wp[t] = ssc[t / HD] * W[t];
    if (t < HD) {
        float acc = 0.0f;
        #pragma unroll
        for (int k = 0; k < HD; ++k) acc = fmaf(ssh[k], W[k * HD + t], acc);
        cvec[t] = acc;
    }
    if (t < 600) {
        int k = t / 10;
        float s = (k < HD) ? scsh1[k] : (k < 2 * HD) ? ssc[k - HD] : 1.0f;
        Wlp[t] = s * Wl[t];
    }
    if (t < 10) {
        float acc = bl[t];
        #pragma unroll
        for (int k = 0; k < HD; ++k) acc = fmaf(scsh1[HD + k], Wl[k * 10 + t], acc);
        #pragma unroll
        for (int k = 0; k < HD; ++k) acc = fmaf(ssh[k], Wl[(HD + k) * 10 + t], acc);
        blp[t] = acc;
    }
}

extern "C" void kernel_launch(void* const* d_in, const int* in_sizes, int n_in,
                              void* d_out, int out_size, void* d_ws, size_t ws_size,
                              hipStream_t stream) {
    const float* x   = (const float*)d_in[0];
    const int*   ei  = (const int*)d_in[1];
    const float* ew  = (const float*)d_in[2];
    const float* W1  = (const float*)d_in[3];
    const float* b1  = (const float*)d_in[4];
    const float* g1  = (const float*)d_in[5];
    const float* be1 = (const float*)d_in[6];
    const float* W2  = (const float*)d_in[7];
    const float* b2  = (const float*)d_in[8];
    const float* g2  = (const float*)d_in[9];
    const float* be2 = (const float*)d_in[10];
    const float* W3  = (const float*)d_in[11];
    const float* b3  = (const float*)d_in[12];
    const float* Wl  = (const float*)d_in[13];
    const float* bl  = (const float*)d_in[14];
    float* out = (float*)d_out;

    const int F = in_sizes[3] / HD;       // 128
    const int N = in_sizes[0] / F;        // 100000
    const int E = in_sizes[2];            // 3200000
    const int* src = ei;
    const int* dst = ei + E;
    const int nbv = (N + 127) >> BSH;     // 782 buckets

    char* p = (char*)d_ws;
    auto alloc = [&](size_t bytes) -> void* {
        void* r = (void*)p;
        p += (bytes + 255) & ~(size_t)255;
        return r;
    };
    size_t nh4 = (size_t)N * HD * 4;                         // 8e6 B
    int2*  se      = (int2*) alloc((size_t)E * 8);           // sorted (src|loc, ew)
    char*  regionA = (char*) alloc((size_t)E * 8);           // tmp -> hs|_|o1r
    float* o2r     = (float*)alloc(nh4);
    float* dinv    = (float*)alloc((size_t)N * 4);
    int*   row_start = (int*)alloc((size_t)(N + 1) * 4);
    int*   bcnt    = (int*)  alloc(NBMAX * 4);
    int*   bstart  = (int*)  alloc((NBMAX + 1) * 4);
    int*   bcur    = (int*)  alloc(NBMAX * 4);
    float* stats   = (float*)alloc(80 * 4);   // sum1,sq1,sum2,sq2
    float* scsh    = (float*)alloc(80 * 4);   // sc1,sh1,sc2,sh2
    float* zero20  = (float*)alloc(20 * 4);
    float* W2p     = (float*)alloc(400 * 4);
    float* c2      = (float*)alloc(20 * 4);
    float* W3p     = (float*)alloc(400 * 4);
    float* c3      = (float*)alloc(20 * 4);
    float* Wlp     = (float*)alloc(600 * 4);
    float* blp     = (float*)alloc(12 * 4);

    int2*   tmp = (int2*)regionA;
    __half* hs  = (__half*)regionA;                 // 4 MB fp16, fits per-XCD L2
    float*  o1r = (float*)(regionA + 2 * nh4);

    const int B = 256;
    const int GB = 512;                          // blocks for hist/scatter
    const int chunk = (E + GB - 1) / GB;         // 6250

    // ---- graph build (shared by all 3 layers) ----
    hipLaunchKernelGGL(init_kernel, dim3(1), dim3(1024), 0, stream, bcnt, stats, zero20, nbv);
    hipLaunchKernelGGL(bucket_hist_kernel, dim3(GB), dim3(B), 0, stream, dst, bcnt, E, chunk, nbv);
    hipLaunchKernelGGL(bucket_scan_kernel, dim3(1), dim3(1024), 0, stream,
                       bcnt, bstart, bcur, row_start, N, E, nbv);
    hipLaunchKernelGGL(scatter_kernel, dim3(GB), dim3(B), 0, stream,
                       src, dst, ew, bcur, tmp, E, chunk, nbv);
    hipLaunchKernelGGL(finalize_kernel, dim3(nbv), dim3(B), 0, stream,
                       tmp, bstart, se, row_start, dinv, N);

    // ---- layer 1 (no upstream BN: cvec = 0, bias = b1) ----
    hipLaunchKernelGGL((gemm_kernel<128, 16>), dim3((N + 15) / 16), dim3(B), 0, stream,
                       x, W1, zero20, dinv, hs, N);
    hipLaunchKernelGGL((agg_kernel<0>), dim3(nbv), dim3(512), 0, stream,
                       hs, dinv, se, bstart, b1, o1r,
                       stats, stats + 20, nullptr, nullptr, nullptr, nullptr, N);
    hipLaunchKernelGGL(bn_adjust_kernel, dim3(1), dim3(512), 0, stream,
                       stats, stats + 20, g1, be1, W2, scsh, W2p, c2, N);

    // ---- layer 2 (BN1 scale in W2p, shift in c2 pre-agg; bias = raw b2) ----
    hipLaunchKernelGGL((gemm_kernel<HD, 64>), dim3((N + 63) / 64), dim3(B), 0, stream,
                       o1r, W2p, c2, dinv, hs, N);
    hipLaunchKernelGGL((agg_kernel<0>), dim3(nbv), dim3(512), 0, stream,
                       hs, dinv, se, bstart, b2, o2r,
                       stats + 40, stats + 60, nullptr, nullptr, nullptr, nullptr, N);
    hipLaunchKernelGGL(bn_adjust2_kernel, dim3(1), dim3(640), 0, stream,
                       stats + 40, stats + 60, g2, be2, W3, scsh + 40, W3p, c3,
                       Wl, bl, scsh, Wlp, blp, N);

    // ---- layer 3 + fused final linear (writes d_out directly) ----
    hipLaunchKernelGGL((gemm_kernel<HD, 64>), dim3((N + 63) / 64), dim3(B), 0, stream,
                       o2r, W3p, c3, dinv, hs, N);
    hipLaunchKernelGGL((agg_kernel<1>), dim3(nbv), dim3(512), 0, stream,
                       hs, dinv, se, bstart, b3, out,
                       nullptr, nullptr, o1r, o2r, Wlp, blp, N);
}

// Round 8
// 581.139 us; speedup vs baseline: 1.0148x; 1.0148x over previous
//
#include <hip/hip_runtime.h>
#include <hip/hip_fp16.h>

// NodeGCN: 3x GCNConv(H=20) + BN/ReLU + final linear, N=100K, E=3.2M.
// R14 (resubmit; prior run was an infra failure) = R11 (513us best) with two
// agg-only MLP fixes:
//  - R13 post-mortem: segmented-reduction agg regressed (107us, VALU 7%) --
//    51.7KB LDS capped occupancy at 25% and depth-2 gave fewer outstanding
//    loads than R8. Owner-computes walk retained.
//  - SPLIT hs TABLES: hsA[N][16] (32B rows) + hsB[N][4] (8B rows). Gather =
//    dwordx4 + dwordx4 + dwordx2, all naturally aligned, no line crossings:
//    3 lane-requests/edge (was 5). Total 4MB -> per-XCD L2 fit preserved.
//  - DEPTH-4 edge pipeline (3 rows in flight/lane): ~2x outstanding loads/CU
//    even if VGPR (~80) caps occupancy at 16 waves/CU.

#define HD 20
#define EPS 1e-5f
#define BSH 7            // 128 nodes per bucket
#define NBMAX 1024
#define CAP 5632         // finalize: max edges per bucket staged in LDS
#define CAPE 2816        // agg: max edges per block staged in LDS (mean ~2048)

typedef float __attribute__((ext_vector_type(4))) f4v;

__device__ __forceinline__ float4 ntld4(const float* p) {
    f4v v = __builtin_nontemporal_load((const f4v*)p);
    return make_float4(v.x, v.y, v.z, v.w);
}

__global__ __launch_bounds__(1024)
void init_kernel(int* bcnt, float* stats, float* zero20, int nbv) {
    int t = threadIdx.x;
    if (t < nbv) bcnt[t] = 0;
    if (t < 80) stats[t] = 0.0f;
    if (t < HD) zero20[t] = 0.0f;
}

__global__ __launch_bounds__(256)
void bucket_hist_kernel(const int* __restrict__ dst, int* __restrict__ bcnt,
                        int E, int chunk, int nbv) {
    __shared__ int lh[NBMAX];
    for (int i = threadIdx.x; i < nbv; i += 256) lh[i] = 0;
    __syncthreads();
    int s = blockIdx.x * chunk;
    int e = s + chunk; if (e > E) e = E;
    for (int j = s + threadIdx.x; j < e; j += 256)
        atomicAdd(&lh[dst[j] >> BSH], 1);
    __syncthreads();
    for (int i = threadIdx.x; i < nbv; i += 256)
        if (lh[i]) atomicAdd(&bcnt[i], lh[i]);
}

// single block: exclusive scan bcnt[0..nbv) -> bstart, init bcur, row_start[N]=E
__global__ __launch_bounds__(1024)
void bucket_scan_kernel(const int* __restrict__ bcnt, int* __restrict__ bstart,
                        int* __restrict__ bcur, int* __restrict__ row_start,
                        int n, int E, int nbv) {
    __shared__ int s[1024];
    int t = threadIdx.x;
    int v = (t < nbv) ? bcnt[t] : 0;
    s[t] = v;
    __syncthreads();
    for (int off = 1; off < 1024; off <<= 1) {
        int u = (t >= off) ? s[t - off] : 0;
        __syncthreads();
        s[t] += u;
        __syncthreads();
    }
    if (t < nbv) { int st = s[t] - v; bstart[t] = st; bcur[t] = st; }
    if (t == 0) { bstart[nbv] = E; row_start[n] = E; }
}

// scatter edges into bucket-grouped tmp; payload packed (src | local<<20, ew)
__global__ __launch_bounds__(256)
void scatter_kernel(const int* __restrict__ src, const int* __restrict__ dst,
                    const float* __restrict__ ew, int* __restrict__ bcur,
                    int2* __restrict__ tmp, int E, int chunk, int nbv) {
    __shared__ int lh[NBMAX];
    __shared__ int lbase[NBMAX];
    for (int i = threadIdx.x; i < nbv; i += 256) lh[i] = 0;
    __syncthreads();
    int s = blockIdx.x * chunk;
    int e = s + chunk; if (e > E) e = E;
    for (int j = s + threadIdx.x; j < e; j += 256)
        atomicAdd(&lh[dst[j] >> BSH], 1);
    __syncthreads();
    for (int i = threadIdx.x; i < nbv; i += 256) {
        int c = lh[i];
        lbase[i] = c ? atomicAdd(&bcur[i], c) : 0;
        lh[i] = 0;                         // reuse as local cursor
    }
    __syncthreads();
    for (int j = s + threadIdx.x; j < e; j += 256) {
        int d = dst[j];
        int b = d >> BSH;
        int pos = atomicAdd(&lh[b], 1);
        tmp[lbase[b] + pos] = make_int2(src[j] | ((d & ((1 << BSH) - 1)) << 20),
                                        __float_as_int(ew[j]));
    }
}

// one block per bucket: in-LDS counting sort by local dst; emit CSR + row_start + dinv
__global__ __launch_bounds__(256)
void finalize_kernel(const int2* __restrict__ tmp, const int* __restrict__ bstart,
                     int2* __restrict__ se, int* __restrict__ row_start,
                     float* __restrict__ dinv, int n) {
    __shared__ int hist[128];
    __shared__ float degs[128];
    __shared__ int off[128];
    __shared__ int cur[128];
    __shared__ int2 stage[CAP];
    int b = blockIdx.x;
    int s0 = bstart[b], s1 = bstart[b + 1];
    int cnt = s1 - s0;
    int t = threadIdx.x;
    if (t < 128) { hist[t] = 0; degs[t] = 0.0f; cur[t] = 0; }
    __syncthreads();
    for (int j = s0 + t; j < s1; j += 256) {
        int2 r = tmp[j];
        int l = r.x >> 20;
        atomicAdd(&hist[l], 1);
        atomicAdd(&degs[l], __int_as_float(r.y));
    }
    __syncthreads();
    if (t < 128) off[t] = hist[t];
    __syncthreads();
    for (int o = 1; o < 128; o <<= 1) {           // inclusive scan
        int u = (t < 128 && t >= o) ? off[t - o] : 0;
        __syncthreads();
        if (t < 128) off[t] += u;
        __syncthreads();
    }
    if (t < 128) {
        int node = (b << BSH) + t;
        if (node < n) {
            row_start[node] = s0 + off[t] - hist[t];   // exclusive
            dinv[node] = rsqrtf(1.0f + degs[t]);
        }
    }
    __syncthreads();
    if (cnt <= CAP) {
        for (int j = s0 + t; j < s1; j += 256) {
            int2 r = tmp[j];
            int l = r.x >> 20;
            int p = (off[l] - hist[l]) + atomicAdd(&cur[l], 1);
            stage[p] = make_int2(r.x & 0xFFFFF, r.y);
        }
        __syncthreads();
        for (int k = t; k < cnt; k += 256) se[s0 + k] = stage[k];
    } else {   // overflow fallback (correctness net; not taken for this input)
        for (int j = s0 + t; j < s1; j += 256) {
            int2 r = tmp[j];
            int l = r.x >> 20;
            int p = (off[l] - hist[l]) + atomicAdd(&cur[l], 1);
            se[s0 + p] = make_int2(r.x & 0xFFFFF, r.y);
        }
    }
}

// hsA[n,16]/hsB[n,4] (fp16) = ((in[n,FIN] @ W[FIN,20]) + cvec) * dinv[n]
template<int FIN, int NPB>
__global__ __launch_bounds__(256)
void gemm_kernel(const float* __restrict__ in, const float* __restrict__ W,
                 const float* __restrict__ cvec, const float* __restrict__ dinv,
                 __half* __restrict__ hsA, __half* __restrict__ hsB, int n) {
    __shared__ float sWt[HD][FIN + 4];
    __shared__ float sIn[NPB][FIN + 4];
    __shared__ float sC[HD];
    for (int i = threadIdx.x; i < FIN * HD; i += 256) {
        int k = i / HD, f = i % HD;           // W row-major [k][f]
        sWt[f][k] = W[i];
    }
    if (threadIdx.x < HD) sC[threadIdx.x] = cvec[threadIdx.x];
    int base = blockIdx.x * NPB;
    int nb = n - base; if (nb > NPB) nb = NPB;
    int lim = n * FIN;
    const int Q = FIN / 4;
    for (int i = threadIdx.x; i < NPB * Q; i += 256) {
        int row = i / Q, c = (i % Q) * 4;
        int g = (base + row) * FIN + c;
        *(float4*)&sIn[row][c] = (g < lim) ? ntld4(&in[g])
                                           : make_float4(0.f, 0.f, 0.f, 0.f);
    }
    __syncthreads();
    for (int idx = threadIdx.x; idx < NPB * HD; idx += 256) {
        int nl = idx / HD, f = idx % HD;
        float4 a = make_float4(0.f, 0.f, 0.f, 0.f);
        #pragma unroll 4
        for (int k = 0; k < FIN; k += 4) {
            float4 x4 = *(const float4*)&sIn[nl][k];
            float4 w4 = *(const float4*)&sWt[f][k];
            a.x = fmaf(x4.x, w4.x, a.x);
            a.y = fmaf(x4.y, w4.y, a.y);
            a.z = fmaf(x4.z, w4.z, a.z);
            a.w = fmaf(x4.w, w4.w, a.w);
        }
        if (nl < nb) {
            __half hv = __float2half_rn(
                (((a.x + a.y) + (a.z + a.w)) + sC[f]) * dinv[base + nl]);
            if (f < 16) hsA[(size_t)(base + nl) * 16 + f] = hv;
            else        hsB[(size_t)(base + nl) * 4 + (f - 16)] = hv;
        }
    }
}

#define FMA4(A, V, W) \
    A.x = fmaf(V.x, W, A.x); A.y = fmaf(V.y, W, A.y); \
    A.z = fmaf(V.z, W, A.z); A.w = fmaf(V.w, W, A.w);

__device__ __forceinline__ float4 h4f2(uint2 u) {
    float2 f0 = __half22float2(*reinterpret_cast<const __half2*>(&u.x));
    float2 f1 = __half22float2(*reinterpret_cast<const __half2*>(&u.y));
    return make_float4(f0.x, f0.y, f1.x, f1.y);
}

// Split-table row gather: dwordx4 + dwordx4 + dwordx2, all naturally aligned.
#define ROWLD(Q0, Q1, Q2, SRC) { \
    const uint4* pa_ = (const uint4*)(hsA + (size_t)(SRC) * 16); \
    Q0 = pa_[0]; Q1 = pa_[1]; \
    Q2 = *(const uint2*)(hsB + (size_t)(SRC) * 4); }

// Edge loop: depth-4 software pipeline (3 rows in flight past the consumed one).
#define AGG_LOOP(EDGEAT)                                                     \
    {                                                                        \
        int2 e0 = EDGEAT(j);                                                 \
        uint4 p0_, p1_; uint2 p2_; ROWLD(p0_, p1_, p2_, e0.x)                \
        int j1 = j + 4; bool v1 = j1 < s1;                                   \
        int2 e1 = EDGEAT(v1 ? j1 : j);                                       \
        uint4 q0_, q1_; uint2 q2_; ROWLD(q0_, q1_, q2_, e1.x)                \
        int j2 = j1 + 4; bool v2 = j2 < s1;                                  \
        int2 e2 = EDGEAT(v2 ? j2 : j);                                       \
        uint4 r0_, r1_; uint2 r2_; ROWLD(r0_, r1_, r2_, e2.x)                \
        while (true) {                                                       \
            int j3 = j2 + 4; bool v3 = j3 < s1;                              \
            int2 e3 = EDGEAT(v3 ? j3 : j);                                   \
            uint4 s0_, s1_; uint2 s2_; ROWLD(s0_, s1_, s2_, e3.x)            \
            float w = __int_as_float(e0.y);                                  \
            float4 u0 = h4f2(make_uint2(p0_.x, p0_.y));                      \
            float4 u1 = h4f2(make_uint2(p0_.z, p0_.w));                      \
            float4 u2 = h4f2(make_uint2(p1_.x, p1_.y));                      \
            float4 u3 = h4f2(make_uint2(p1_.z, p1_.w));                      \
            float4 u4 = h4f2(p2_);                                           \
            FMA4(a0, u0, w) FMA4(a1, u1, w) FMA4(a2, u2, w)                  \
            FMA4(a3, u3, w) FMA4(a4, u4, w)                                  \
            if (!v1) break;                                                  \
            e0 = e1; p0_ = q0_; p1_ = q1_; p2_ = q2_;                        \
            e1 = e2; q0_ = r0_; q1_ = r1_; q2_ = r2_; v1 = v2;               \
            e2 = e3; r0_ = s0_; r1_ = s1_; r2_ = s2_; v2 = v3; j2 = j3;      \
        }                                                                    \
    }

#define EDGE_LDS(jj) sse[(jj) - sb0]
#define EDGE_GBL(jj) se[(jj)]

// MODE 0: layers 1/2 — write o row + BN stats.
// MODE 1: layer 3 — fuse final linear: out[i,0..9] from o1,o2 rows + in-reg o3.
// One node per 4-lane group; block's 64 nodes = contiguous se span staged in LDS.
template<int MODE>
__global__ __launch_bounds__(256)
void agg_kernel(const __half* __restrict__ hsA, const __half* __restrict__ hsB,
                const float* __restrict__ dinv,
                const int* __restrict__ row_start, const int2* __restrict__ se,
                const float* __restrict__ bias, float* __restrict__ out,
                float* __restrict__ stat_sum, float* __restrict__ stat_sq,
                const float* __restrict__ o1, const float* __restrict__ o2,
                const float* __restrict__ Wlp, const float* __restrict__ blp,
                int n) {
    __shared__ int2 sse[CAPE];
    __shared__ float ls[HD], lq[HD];
    __shared__ float sW[600];
    __shared__ float sb[10];
    int base = blockIdx.x * 64;              // 256 threads / 4 lanes = 64 nodes
    int nEnd = base + 64; if (nEnd > n) nEnd = n;
    int sb0 = row_start[base];
    int sb1 = row_start[nEnd];
    int span = sb1 - sb0;
    bool ok = (span <= CAPE);
    if (MODE == 0) {
        if (threadIdx.x < HD) { ls[threadIdx.x] = 0.0f; lq[threadIdx.x] = 0.0f; }
    } else {
        for (int i = threadIdx.x; i < 600; i += 256) sW[i] = Wlp[i];
        if (threadIdx.x < 10) sb[threadIdx.x] = blp[threadIdx.x];
    }
    if (ok) {
        for (int k = threadIdx.x; k < span; k += 256) {
            long long v = __builtin_nontemporal_load(
                (const long long*)(se + sb0 + k));
            sse[k] = *(const int2*)&v;
        }
    }
    __syncthreads();
    int i = base + (threadIdx.x >> 2), lane = threadIdx.x & 3;
    if (i < n) {
        float di = dinv[i];
        int s0 = row_start[i], s1 = row_start[i + 1];
        float4 a0, a1, a2, a3, a4;
        if (lane == 0) {
            uint4 y0, y1; uint2 y2;
            ROWLD(y0, y1, y2, i)
            a0 = h4f2(make_uint2(y0.x, y0.y));
            a1 = h4f2(make_uint2(y0.z, y0.w));
            a2 = h4f2(make_uint2(y1.x, y1.y));
            a3 = h4f2(make_uint2(y1.z, y1.w));
            a4 = h4f2(y2);
        } else {
            a0 = a1 = a2 = a3 = a4 = make_float4(0.f, 0.f, 0.f, 0.f);
        }
        int j = s0 + lane;
        if (j < s1) {
            if (ok) { AGG_LOOP(EDGE_LDS) }
            else    { AGG_LOOP(EDGE_GBL) }
        }
        #define REDX(A, M) \
            A.x += __shfl_xor(A.x, M); A.y += __shfl_xor(A.y, M); \
            A.z += __shfl_xor(A.z, M); A.w += __shfl_xor(A.w, M);
        #define RED4L(A) REDX(A, 1) REDX(A, 2)
        RED4L(a0) RED4L(a1) RED4L(a2) RED4L(a3) RED4L(a4)
        // all 4 lanes now hold the full sums
        float4 acc[5] = {a0, a1, a2, a3, a4};
        float va[HD];
        #pragma unroll
        for (int q = 0; q < 5; ++q) {
            float4 bb = *(const float4*)(bias + 4 * q);
            va[4 * q + 0] = fmaxf(fmaf(acc[q].x, di, bb.x), 0.0f);
            va[4 * q + 1] = fmaxf(fmaf(acc[q].y, di, bb.y), 0.0f);
            va[4 * q + 2] = fmaxf(fmaf(acc[q].z, di, bb.z), 0.0f);
            va[4 * q + 3] = fmaxf(fmaf(acc[q].w, di, bb.w), 0.0f);
        }
        if (MODE == 0) {
            if (lane == 0) {
                #pragma unroll
                for (int q = 0; q < 5; ++q) {
                    ((float4*)out)[i * 5 + q] = make_float4(
                        va[4 * q], va[4 * q + 1], va[4 * q + 2], va[4 * q + 3]);
                    int f = 4 * q;
                    atomicAdd(&ls[f + 0], va[f + 0]); atomicAdd(&lq[f + 0], va[f + 0] * va[f + 0]);
                    atomicAdd(&ls[f + 1], va[f + 1]); atomicAdd(&lq[f + 1], va[f + 1] * va[f + 1]);
                    atomicAdd(&ls[f + 2], va[f + 2]); atomicAdd(&lq[f + 2], va[f + 2] * va[f + 2]);
                    atomicAdd(&ls[f + 3], va[f + 3]); atomicAdd(&lq[f + 3], va[f + 3] * va[f + 3]);
                }
            }
        } else {
            // fused final: load o1,o2 rows (same addrs across quad -> L1 broadcast)
            float r1[HD], r2[HD];
            #pragma unroll
            for (int q = 0; q < 5; ++q) {
                *(float4*)&r1[4 * q] = ((const float4*)(o1 + (size_t)i * HD))[q];
                *(float4*)&r2[4 * q] = ((const float4*)(o2 + (size_t)i * HD))[q];
            }
            for (int c = lane; c < 10; c += 4) {
                float s = sb[c];
                #pragma unroll
                for (int k = 0; k < HD; ++k) s = fmaf(r1[k], sW[k * 10 + c], s);
                #pragma unroll
                for (int k = 0; k < HD; ++k) s = fmaf(r2[k], sW[(HD + k) * 10 + c], s);
                #pragma unroll
                for (int k = 0; k < HD; ++k) s = fmaf(va[k], sW[(2 * HD + k) * 10 + c], s);
                out[(size_t)i * 10 + c] = s;
            }
        }
    }
    if (MODE == 0) {
        __syncthreads();
        if (threadIdx.x < HD) {
            atomicAdd(&stat_sum[threadIdx.x], ls[threadIdx.x]);
            atomicAdd(&stat_sq[threadIdx.x], lq[threadIdx.x]);
        }
    }
}

// BN finalize + fold into next conv: scsh_out = (scale,shift);
// Wp[k][f] = sc[k]*W[k][f]; cvec[f] = sum_k sh[k]*W[k][f]
__global__ __launch_bounds__(512)
void bn_adjust_kernel(const float* __restrict__ sum, const float* __restrict__ sq,
                      const float* __restrict__ g, const float* __restrict__ be,
                      const float* __restrict__ W, float* __restrict__ scsh_out,
                      float* __restrict__ Wp, float* __restrict__ cvec, int n) {
    __shared__ float ssc[HD], ssh[HD];
    int t = threadIdx.x;
    if (t < HD) {
        float inv_n = 1.0f / (float)n;
        float m = sum[t] * inv_n;
        float var = sq[t] * inv_n - m * m;
        float sc = g[t] * rsqrtf(var + EPS);
        float sh = be[t] - m * sc;
        ssc[t] = sc; ssh[t] = sh;
        scsh_out[t] = sc; scsh_out[HD + t] = sh;
    }
    __syncthreads();
    if (t < HD * HD) Wp[t] = ssc[t / HD] * W[t];
    if (t < HD) {
        float acc = 0.0f;
        #pragma unroll
        for (int k = 0; k < HD; ++k) acc = fmaf(ssh[k], W[k * HD + t], acc);
        cvec[t] = acc;
    }
}

// second BN: same as above + build Wlp/blp for the fused final.
// Wlp rows: 0..19 *= sc1, 20..39 *= sc2, 40..59 UNSCALED (o3 block).
__global__ __launch_bounds__(640)
void bn_adjust2_kernel(const float* __restrict__ sum, const float* __restrict__ sq,
                       const float* __restrict__ g, const float* __restrict__ be,
                       const float* __restrict__ W, float* __restrict__ scsh_out,
                       float* __restrict__ Wp, float* __restrict__ cvec,
                       const float* __restrict__ Wl, const float* __restrict__ bl,
                       const float* __restrict__ scsh1,
                       float* __restrict__ Wlp, float* __restrict__ blp, int n) {
    __shared__ float ssc[HD], ssh[HD];
    int t = threadIdx.x;
    if (t < HD) {
        float inv_n = 1.0f / (float)n;
        float m = sum[t] * inv_n;
        float var = sq[t] * inv_n - m * m;
        float sc = g[t] * rsqrtf(var + EPS);
        float sh = be[t] - m * sc;
        ssc[t] = sc; ssh[t] = sh;
        scsh_out[t] = sc; scsh_out[HD + t] = sh;
    }
    __syncthreads();
    if (t < HD * HD) Wp[t] = ssc[t / HD] * W[t];
    if (t < HD) {
        float acc = 0.0f;
        #pragma unroll
        for (int k = 0; k < HD; ++k) acc = fmaf(ssh[k], W[k * HD + t], acc);
        cvec[t] = acc;
    }
    if (t < 600) {
        int k = t / 10;
        float s = (k < HD) ? scsh1[k] : (k < 2 * HD) ? ssc[k - HD] : 1.0f;
        Wlp[t] = s * Wl[t];
    }
    if (t < 10) {
        float acc = bl[t];
        #pragma unroll
        for (int k = 0; k < HD; ++k) acc = fmaf(scsh1[HD + k], Wl[k * 10 + t], acc);
        #pragma unroll
        for (int k = 0; k < HD; ++k) acc = fmaf(ssh[k], Wl[(HD + k) * 10 + t], acc);
        blp[t] = acc;
    }
}

extern "C" void kernel_launch(void* const* d_in, const int* in_sizes, int n_in,
                              void* d_out, int out_size, void* d_ws, size_t ws_size,
                              hipStream_t stream) {
    const float* x   = (const float*)d_in[0];
    const int*   ei  = (const int*)d_in[1];
    const float* ew  = (const float*)d_in[2];
    const float* W1  = (const float*)d_in[3];
    const float* b1  = (const float*)d_in[4];
    const float* g1  = (const float*)d_in[5];
    const float* be1 = (const float*)d_in[6];
    const float* W2  = (const float*)d_in[7];
    const float* b2  = (const float*)d_in[8];
    const float* g2  = (const float*)d_in[9];
    const float* be2 = (const float*)d_in[10];
    const float* W3  = (const float*)d_in[11];
    const float* b3  = (const float*)d_in[12];
    const float* Wl  = (const float*)d_in[13];
    const float* bl  = (const float*)d_in[14];
    float* out = (float*)d_out;

    const int F = in_sizes[3] / HD;       // 128
    const int N = in_sizes[0] / F;        // 100000
    const int E = in_sizes[2];            // 3200000
    const int* src = ei;
    const int* dst = ei + E;
    const int nbv = (N + 127) >> BSH;     // 782 buckets

    char* p = (char*)d_ws;
    auto alloc = [&](size_t bytes) -> void* {
        void* r = (void*)p;
        p += (bytes + 255) & ~(size_t)255;
        return r;
    };
    size_t nh4 = (size_t)N * HD * 4;                         // 8e6 B
    int2*  se      = (int2*) alloc((size_t)E * 8);           // CSR payload (src, ew)
    char*  regionA = (char*) alloc((size_t)E * 8);           // tmp -> hsA|hsB|_|o1r
    float* o2r     = (float*)alloc(nh4);
    float* dinv    = (float*)alloc((size_t)N * 4);
    int*   row_start = (int*)alloc((size_t)(N + 1) * 4);
    int*   bcnt    = (int*)  alloc(NBMAX * 4);
    int*   bstart  = (int*)  alloc((NBMAX + 1) * 4);
    int*   bcur    = (int*)  alloc(NBMAX * 4);
    float* stats   = (float*)alloc(80 * 4);   // sum1,sq1,sum2,sq2
    float* scsh    = (float*)alloc(80 * 4);   // sc1,sh1,sc2,sh2
    float* zero20  = (float*)alloc(20 * 4);
    float* W2p     = (float*)alloc(400 * 4);
    float* c2      = (float*)alloc(20 * 4);
    float* W3p     = (float*)alloc(400 * 4);
    float* c3      = (float*)alloc(20 * 4);
    float* Wlp     = (float*)alloc(600 * 4);
    float* blp     = (float*)alloc(12 * 4);

    int2*   tmp = (int2*)regionA;
    __half* hsA = (__half*)regionA;                      // 3.2 MB (32B rows)
    __half* hsB = (__half*)(regionA + (size_t)N * 32);   // 0.8 MB (8B rows)
    float*  o1r = (float*)(regionA + 2 * nh4);           // at 16 MB

    const int B = 256;
    const int GB = 512;                          // blocks for hist/scatter
    const int chunk = (E + GB - 1) / GB;         // 6250
    int gAgg = (4 * N + B - 1) / B;              // 1563 (4 lanes/node, 64 nodes/block)

    // ---- graph build (shared by all 3 layers) ----
    hipLaunchKernelGGL(init_kernel, dim3(1), dim3(1024), 0, stream, bcnt, stats, zero20, nbv);
    hipLaunchKernelGGL(bucket_hist_kernel, dim3(GB), dim3(B), 0, stream, dst, bcnt, E, chunk, nbv);
    hipLaunchKernelGGL(bucket_scan_kernel, dim3(1), dim3(1024), 0, stream,
                       bcnt, bstart, bcur, row_start, N, E, nbv);
    hipLaunchKernelGGL(scatter_kernel, dim3(GB), dim3(B), 0, stream,
                       src, dst, ew, bcur, tmp, E, chunk, nbv);
    hipLaunchKernelGGL(finalize_kernel, dim3(nbv), dim3(B), 0, stream,
                       tmp, bstart, se, row_start, dinv, N);

    // ---- layer 1 (no upstream BN: cvec = 0, bias = b1) ----
    hipLaunchKernelGGL((gemm_kernel<128, 16>), dim3((N + 15) / 16), dim3(B), 0, stream,
                       x, W1, zero20, dinv, hsA, hsB, N);
    hipLaunchKernelGGL((agg_kernel<0>), dim3(gAgg), dim3(B), 0, stream,
                       hsA, hsB, dinv, row_start, se, b1, o1r,
                       stats, stats + 20, nullptr, nullptr, nullptr, nullptr, N);
    hipLaunchKernelGGL(bn_adjust_kernel, dim3(1), dim3(512), 0, stream,
                       stats, stats + 20, g1, be1, W2, scsh, W2p, c2, N);

    // ---- layer 2 (BN1 scale in W2p, shift in c2 pre-agg; bias = raw b2) ----
    hipLaunchKernelGGL((gemm_kernel<HD, 64>), dim3((N + 63) / 64), dim3(B), 0, stream,
                       o1r, W2p, c2, dinv, hsA, hsB, N);
    hipLaunchKernelGGL((agg_kernel<0>), dim3(gAgg), dim3(B), 0, stream,
                       hsA, hsB, dinv, row_start, se, b2, o2r,
                       stats + 40, stats + 60, nullptr, nullptr, nullptr, nullptr, N);
    hipLaunchKernelGGL(bn_adjust2_kernel, dim3(1), dim3(640), 0, stream,
                       stats + 40, stats + 60, g2, be2, W3, scsh + 40, W3p, c3,
                       Wl, bl, scsh, Wlp, blp, N);

    // ---- layer 3 + fused final linear (writes d_out directly) ----
    hipLaunchKernelGGL((gemm_kernel<HD, 64>), dim3((N + 63) / 64), dim3(B), 0, stream,
                       o2r, W3p, c3, dinv, hsA, hsB, N);
    hipLaunchKernelGGL((agg_kernel<1>), dim3(gAgg), dim3(B), 0, stream,
                       hsA, hsB, dinv, row_start, se, b3, out,
                       nullptr, nullptr, o1r, o2r, Wlp, blp, N);
}

// Round 9
// 523.153 us; speedup vs baseline: 1.1273x; 1.1108x over previous
//
#include <hip/hip_runtime.h>
#include <hip/hip_fp16.h>

// NodeGCN: 3x GCNConv(H=20) + BN/ReLU + final linear, N=100K, E=3.2M.
// R15 = R11 (513us best) with ONE change: hs rows padded to 64B (HSS=32).
//  - Cross-round model: agg time tracks L2 LINES touched per edge, not
//    lane-requests (R12: 5->3 req flat; R14: 1.63->2.5 lines = +35%).
//    64B-aligned rows => exactly 1 line/edge (was ~1.63). Predicted agg
//    88 -> ~55-65us if the line model holds; flat/worse if per-XCD L2
//    residency (hs 4->6.4MB) dominates. Discriminating experiment.
//  - Depth-2 pipeline and 4 lanes/node retained (R10/R14 depth/lane
//    experiments both regressed). Everything else identical to R11.

#define HD 20
#define HSS 32           // hs row stride in halves (64 B, line-aligned)
#define EPS 1e-5f
#define BSH 7            // 128 nodes per bucket
#define NBMAX 1024
#define CAP 5632         // finalize: max edges per bucket staged in LDS
#define CAPE 2816        // agg: max edges per block staged in LDS (mean ~2048)

typedef float __attribute__((ext_vector_type(4))) f4v;

__device__ __forceinline__ float4 ntld4(const float* p) {
    f4v v = __builtin_nontemporal_load((const f4v*)p);
    return make_float4(v.x, v.y, v.z, v.w);
}

__global__ __launch_bounds__(1024)
void init_kernel(int* bcnt, float* stats, float* zero20, int nbv) {
    int t = threadIdx.x;
    if (t < nbv) bcnt[t] = 0;
    if (t < 80) stats[t] = 0.0f;
    if (t < HD) zero20[t] = 0.0f;
}

__global__ __launch_bounds__(256)
void bucket_hist_kernel(const int* __restrict__ dst, int* __restrict__ bcnt,
                        int E, int chunk, int nbv) {
    __shared__ int lh[NBMAX];
    for (int i = threadIdx.x; i < nbv; i += 256) lh[i] = 0;
    __syncthreads();
    int s = blockIdx.x * chunk;
    int e = s + chunk; if (e > E) e = E;
    for (int j = s + threadIdx.x; j < e; j += 256)
        atomicAdd(&lh[dst[j] >> BSH], 1);
    __syncthreads();
    for (int i = threadIdx.x; i < nbv; i += 256)
        if (lh[i]) atomicAdd(&bcnt[i], lh[i]);
}

// single block: exclusive scan bcnt[0..nbv) -> bstart, init bcur, row_start[N]=E
__global__ __launch_bounds__(1024)
void bucket_scan_kernel(const int* __restrict__ bcnt, int* __restrict__ bstart,
                        int* __restrict__ bcur, int* __restrict__ row_start,
                        int n, int E, int nbv) {
    __shared__ int s[1024];
    int t = threadIdx.x;
    int v = (t < nbv) ? bcnt[t] : 0;
    s[t] = v;
    __syncthreads();
    for (int off = 1; off < 1024; off <<= 1) {
        int u = (t >= off) ? s[t - off] : 0;
        __syncthreads();
        s[t] += u;
        __syncthreads();
    }
    if (t < nbv) { int st = s[t] - v; bstart[t] = st; bcur[t] = st; }
    if (t == 0) { bstart[nbv] = E; row_start[n] = E; }
}

// scatter edges into bucket-grouped tmp; payload packed (src | local<<20, ew)
__global__ __launch_bounds__(256)
void scatter_kernel(const int* __restrict__ src, const int* __restrict__ dst,
                    const float* __restrict__ ew, int* __restrict__ bcur,
                    int2* __restrict__ tmp, int E, int chunk, int nbv) {
    __shared__ int lh[NBMAX];
    __shared__ int lbase[NBMAX];
    for (int i = threadIdx.x; i < nbv; i += 256) lh[i] = 0;
    __syncthreads();
    int s = blockIdx.x * chunk;
    int e = s + chunk; if (e > E) e = E;
    for (int j = s + threadIdx.x; j < e; j += 256)
        atomicAdd(&lh[dst[j] >> BSH], 1);
    __syncthreads();
    for (int i = threadIdx.x; i < nbv; i += 256) {
        int c = lh[i];
        lbase[i] = c ? atomicAdd(&bcur[i], c) : 0;
        lh[i] = 0;                         // reuse as local cursor
    }
    __syncthreads();
    for (int j = s + threadIdx.x; j < e; j += 256) {
        int d = dst[j];
        int b = d >> BSH;
        int pos = atomicAdd(&lh[b], 1);
        tmp[lbase[b] + pos] = make_int2(src[j] | ((d & ((1 << BSH) - 1)) << 20),
                                        __float_as_int(ew[j]));
    }
}

// one block per bucket: in-LDS counting sort by local dst; emit CSR + row_start + dinv
__global__ __launch_bounds__(256)
void finalize_kernel(const int2* __restrict__ tmp, const int* __restrict__ bstart,
                     int2* __restrict__ se, int* __restrict__ row_start,
                     float* __restrict__ dinv, int n) {
    __shared__ int hist[128];
    __shared__ float degs[128];
    __shared__ int off[128];
    __shared__ int cur[128];
    __shared__ int2 stage[CAP];
    int b = blockIdx.x;
    int s0 = bstart[b], s1 = bstart[b + 1];
    int cnt = s1 - s0;
    int t = threadIdx.x;
    if (t < 128) { hist[t] = 0; degs[t] = 0.0f; cur[t] = 0; }
    __syncthreads();
    for (int j = s0 + t; j < s1; j += 256) {
        int2 r = tmp[j];
        int l = r.x >> 20;
        atomicAdd(&hist[l], 1);
        atomicAdd(&degs[l], __int_as_float(r.y));
    }
    __syncthreads();
    if (t < 128) off[t] = hist[t];
    __syncthreads();
    for (int o = 1; o < 128; o <<= 1) {           // inclusive scan
        int u = (t < 128 && t >= o) ? off[t - o] : 0;
        __syncthreads();
        if (t < 128) off[t] += u;
        __syncthreads();
    }
    if (t < 128) {
        int node = (b << BSH) + t;
        if (node < n) {
            row_start[node] = s0 + off[t] - hist[t];   // exclusive
            dinv[node] = rsqrtf(1.0f + degs[t]);
        }
    }
    __syncthreads();
    if (cnt <= CAP) {
        for (int j = s0 + t; j < s1; j += 256) {
            int2 r = tmp[j];
            int l = r.x >> 20;
            int p = (off[l] - hist[l]) + atomicAdd(&cur[l], 1);
            stage[p] = make_int2(r.x & 0xFFFFF, r.y);
        }
        __syncthreads();
        for (int k = t; k < cnt; k += 256) se[s0 + k] = stage[k];
    } else {   // overflow fallback (correctness net; not taken for this input)
        for (int j = s0 + t; j < s1; j += 256) {
            int2 r = tmp[j];
            int l = r.x >> 20;
            int p = (off[l] - hist[l]) + atomicAdd(&cur[l], 1);
            se[s0 + p] = make_int2(r.x & 0xFFFFF, r.y);
        }
    }
}

// hs[n,HSS](fp16) = ((in[n,FIN] @ W[FIN,20]) + cvec) * dinv[n]  (cols 20..31 unused)
template<int FIN, int NPB>
__global__ __launch_bounds__(256)
void gemm_kernel(const float* __restrict__ in, const float* __restrict__ W,
                 const float* __restrict__ cvec, const float* __restrict__ dinv,
                 __half* __restrict__ hs, int n) {
    __shared__ float sWt[HD][FIN + 4];
    __shared__ float sIn[NPB][FIN + 4];
    __shared__ float sC[HD];
    for (int i = threadIdx.x; i < FIN * HD; i += 256) {
        int k = i / HD, f = i % HD;           // W row-major [k][f]
        sWt[f][k] = W[i];
    }
    if (threadIdx.x < HD) sC[threadIdx.x] = cvec[threadIdx.x];
    int base = blockIdx.x * NPB;
    int nb = n - base; if (nb > NPB) nb = NPB;
    int lim = n * FIN;
    const int Q = FIN / 4;
    for (int i = threadIdx.x; i < NPB * Q; i += 256) {
        int row = i / Q, c = (i % Q) * 4;
        int g = (base + row) * FIN + c;
        *(float4*)&sIn[row][c] = (g < lim) ? ntld4(&in[g])
                                           : make_float4(0.f, 0.f, 0.f, 0.f);
    }
    __syncthreads();
    for (int idx = threadIdx.x; idx < NPB * HD; idx += 256) {
        int nl = idx / HD, f = idx % HD;
        float4 a = make_float4(0.f, 0.f, 0.f, 0.f);
        #pragma unroll 4
        for (int k = 0; k < FIN; k += 4) {
            float4 x4 = *(const float4*)&sIn[nl][k];
            float4 w4 = *(const float4*)&sWt[f][k];
            a.x = fmaf(x4.x, w4.x, a.x);
            a.y = fmaf(x4.y, w4.y, a.y);
            a.z = fmaf(x4.z, w4.z, a.z);
            a.w = fmaf(x4.w, w4.w, a.w);
        }
        if (nl < nb)
            hs[(size_t)(base + nl) * HSS + f] = __float2half_rn(
                (((a.x + a.y) + (a.z + a.w)) + sC[f]) * dinv[base + nl]);
    }
}

#define FMA4(A, V, W) \
    A.x = fmaf(V.x, W, A.x); A.y = fmaf(V.y, W, A.y); \
    A.z = fmaf(V.z, W, A.z); A.w = fmaf(V.w, W, A.w);

__device__ __forceinline__ float4 h4f2(uint2 u) {
    float2 f0 = __half22float2(*reinterpret_cast<const __half2*>(&u.x));
    float2 f1 = __half22float2(*reinterpret_cast<const __half2*>(&u.y));
    return make_float4(f0.x, f0.y, f1.x, f1.y);
}

// 64B-aligned row gather: dwordx4 + dwordx4 + dwordx2, all in ONE cache line.
#define ROWLD(Q0, Q1, Q2, SRC) { \
    const uint4* pa_ = (const uint4*)(hsb + (size_t)(SRC) * HSS); \
    Q0 = pa_[0]; Q1 = pa_[1]; \
    Q2 = *(const uint2*)(pa_ + 2); }

// Edge loop: depth-2 software pipeline (next edge + row in flight).
#define AGG_LOOP(EDGEAT)                                                     \
    {                                                                        \
        int2 e = EDGEAT(j);                                                  \
        float w = __int_as_float(e.y);                                       \
        uint4 c0, c1; uint2 c2; ROWLD(c0, c1, c2, e.x)                       \
        while (true) {                                                       \
            int jn = j + 4;                                                  \
            bool more = jn < s1;                                             \
            int jp = more ? jn : j;          /* clamp: re-load warm row */   \
            int2 en = EDGEAT(jp);                                            \
            uint4 n0, n1; uint2 n2; ROWLD(n0, n1, n2, en.x)                  \
            float wn = __int_as_float(en.y);                                 \
            float4 v0 = h4f2(make_uint2(c0.x, c0.y));                        \
            float4 v1 = h4f2(make_uint2(c0.z, c0.w));                        \
            float4 v2 = h4f2(make_uint2(c1.x, c1.y));                        \
            float4 v3 = h4f2(make_uint2(c1.z, c1.w));                        \
            float4 v4 = h4f2(c2);                                            \
            FMA4(a0, v0, w) FMA4(a1, v1, w) FMA4(a2, v2, w)                  \
            FMA4(a3, v3, w) FMA4(a4, v4, w)                                  \
            if (!more) break;                                                \
            j = jn; w = wn;                                                  \
            c0 = n0; c1 = n1; c2 = n2;                                       \
        }                                                                    \
    }

#define EDGE_LDS(jj) sse[(jj) - sb0]
#define EDGE_GBL(jj) se[(jj)]

// MODE 0: layers 1/2 — write o row + BN stats.
// MODE 1: layer 3 — fuse final linear: out[i,0..9] from o1,o2 rows + in-reg o3.
// One node per 4-lane group; block's 64 nodes = contiguous se span staged in LDS.
template<int MODE>
__global__ __launch_bounds__(256)
void agg_kernel(const __half* __restrict__ hsb, const float* __restrict__ dinv,
                const int* __restrict__ row_start, const int2* __restrict__ se,
                const float* __restrict__ bias, float* __restrict__ out,
                float* __restrict__ stat_sum, float* __restrict__ stat_sq,
                const float* __restrict__ o1, const float* __restrict__ o2,
                const float* __restrict__ Wlp, const float* __restrict__ blp,
                int n) {
    __shared__ int2 sse[CAPE];
    __shared__ float ls[HD], lq[HD];
    __shared__ float sW[600];
    __shared__ float sb[10];
    int base = blockIdx.x * 64;              // 256 threads / 4 lanes = 64 nodes
    int nEnd = base + 64; if (nEnd > n) nEnd = n;
    int sb0 = row_start[base];
    int sb1 = row_start[nEnd];
    int span = sb1 - sb0;
    bool ok = (span <= CAPE);
    if (MODE == 0) {
        if (threadIdx.x < HD) { ls[threadIdx.x] = 0.0f; lq[threadIdx.x] = 0.0f; }
    } else {
        for (int i = threadIdx.x; i < 600; i += 256) sW[i] = Wlp[i];
        if (threadIdx.x < 10) sb[threadIdx.x] = blp[threadIdx.x];
    }
    if (ok) {
        for (int k = threadIdx.x; k < span; k += 256) {
            long long v = __builtin_nontemporal_load(
                (const long long*)(se + sb0 + k));
            sse[k] = *(const int2*)&v;
        }
    }
    __syncthreads();
    int i = base + (threadIdx.x >> 2), lane = threadIdx.x & 3;
    if (i < n) {
        float di = dinv[i];
        int s0 = row_start[i], s1 = row_start[i + 1];
        float4 a0, a1, a2, a3, a4;
        if (lane == 0) {
            uint4 y0, y1; uint2 y2;
            ROWLD(y0, y1, y2, i)
            a0 = h4f2(make_uint2(y0.x, y0.y));
            a1 = h4f2(make_uint2(y0.z, y0.w));
            a2 = h4f2(make_uint2(y1.x, y1.y));
            a3 = h4f2(make_uint2(y1.z, y1.w));
            a4 = h4f2(y2);
        } else {
            a0 = a1 = a2 = a3 = a4 = make_float4(0.f, 0.f, 0.f, 0.f);
        }
        int j = s0 + lane;
        if (j < s1) {
            if (ok) { AGG_LOOP(EDGE_LDS) }
            else    { AGG_LOOP(EDGE_GBL) }
        }
        #define REDX(A, M) \
            A.x += __shfl_xor(A.x, M); A.y += __shfl_xor(A.y, M); \
            A.z += __shfl_xor(A.z, M); A.w += __shfl_xor(A.w, M);
        #define RED4L(A) REDX(A, 1) REDX(A, 2)
        RED4L(a0) RED4L(a1) RED4L(a2) RED4L(a3) RED4L(a4)
        // all 4 lanes now hold the full sums
        float4 acc[5] = {a0, a1, a2, a3, a4};
        float va[HD];
        #pragma unroll
        for (int q = 0; q < 5; ++q) {
            float4 bb = *(const float4*)(bias + 4 * q);
            va[4 * q + 0] = fmaxf(fmaf(acc[q].x, di, bb.x), 0.0f);
            va[4 * q + 1] = fmaxf(fmaf(acc[q].y, di, bb.y), 0.0f);
            va[4 * q + 2] = fmaxf(fmaf(acc[q].z, di, bb.z), 0.0f);
            va[4 * q + 3] = fmaxf(fmaf(acc[q].w, di, bb.w), 0.0f);
        }
        if (MODE == 0) {
            if (lane == 0) {
                #pragma unroll
                for (int q = 0; q < 5; ++q) {
                    ((float4*)out)[i * 5 + q] = make_float4(
                        va[4 * q], va[4 * q + 1], va[4 * q + 2], va[4 * q + 3]);
                    int f = 4 * q;
                    atomicAdd(&ls[f + 0], va[f + 0]); atomicAdd(&lq[f + 0], va[f + 0] * va[f + 0]);
                    atomicAdd(&ls[f + 1], va[f + 1]); atomicAdd(&lq[f + 1], va[f + 1] * va[f + 1]);
                    atomicAdd(&ls[f + 2], va[f + 2]); atomicAdd(&lq[f + 2], va[f + 2] * va[f + 2]);
                    atomicAdd(&ls[f + 3], va[f + 3]); atomicAdd(&lq[f + 3], va[f + 3] * va[f + 3]);
                }
            }
        } else {
            // fused final: load o1,o2 rows (same addrs across quad -> L1 broadcast)
            float r1[HD], r2[HD];
            #pragma unroll
            for (int q = 0; q < 5; ++q) {
                *(float4*)&r1[4 * q] = ((const float4*)(o1 + (size_t)i * HD))[q];
                *(float4*)&r2[4 * q] = ((const float4*)(o2 + (size_t)i * HD))[q];
            }
            for (int c = lane; c < 10; c += 4) {
                float s = sb[c];
                #pragma unroll
                for (int k = 0; k < HD; ++k) s = fmaf(r1[k], sW[k * 10 + c], s);
                #pragma unroll
                for (int k = 0; k < HD; ++k) s = fmaf(r2[k], sW[(HD + k) * 10 + c], s);
                #pragma unroll
                for (int k = 0; k < HD; ++k) s = fmaf(va[k], sW[(2 * HD + k) * 10 + c], s);
                out[(size_t)i * 10 + c] = s;
            }
        }
    }
    if (MODE == 0) {
        __syncthreads();
        if (threadIdx.x < HD) {
            atomicAdd(&stat_sum[threadIdx.x], ls[threadIdx.x]);
            atomicAdd(&stat_sq[threadIdx.x], lq[threadIdx.x]);
        }
    }
}

// BN finalize + fold into next conv: scsh_out = (scale,shift);
// Wp[k][f] = sc[k]*W[k][f]; cvec[f] = sum_k sh[k]*W[k][f]
__global__ __launch_bounds__(512)
void bn_adjust_kernel(const float* __restrict__ sum, const float* __restrict__ sq,
                      const float* __restrict__ g, const float* __restrict__ be,
                      const float* __restrict__ W, float* __restrict__ scsh_out,
                      float* __restrict__ Wp, float* __restrict__ cvec, int n) {
    __shared__ float ssc[HD], ssh[HD];
    int t = threadIdx.x;
    if (t < HD) {
        float inv_n = 1.0f / (float)n;
        float m = sum[t] * inv_n;
        float var = sq[t] * inv_n - m * m;
        float sc = g[t] * rsqrtf(var + EPS);
        float sh = be[t] - m * sc;
        ssc[t] = sc; ssh[t] = sh;
        scsh_out[t] = sc; scsh_out[HD + t] = sh;
    }
    __syncthreads();
    if (t < HD * HD) Wp[t] = ssc[t / HD] * W[t];
    if (t < HD) {
        float acc = 0.0f;
        #pragma unroll
        for (int k = 0; k < HD; ++k) acc = fmaf(ssh[k], W[k * HD + t], acc);
        cvec[t] = acc;
    }
}

// second BN: same as above + build Wlp/blp for the fused final.
// Wlp rows: 0..19 *= sc1, 20..39 *= sc2, 40..59 UNSCALED (o3 block).
__global__ __launch_bounds__(640)
void bn_adjust2_kernel(const float* __restrict__ sum, const float* __restrict__ sq,
                       const float* __restrict__ g, const float* __restrict__ be,
                       const float* __restrict__ W, float* __restrict__ scsh_out,
                       float* __restrict__ Wp, float* __restrict__ cvec,
                       const float* __restrict__ Wl, const float* __restrict__ bl,
                       const float* __restrict__ scsh1,
                       float* __restrict__ Wlp, float* __restrict__ blp, int n) {
    __shared__ float ssc[HD], ssh[HD];
    int t = threadIdx.x;
    if (t < HD) {
        float inv_n = 1.0f / (float)n;
        float m = sum[t] * inv_n;
        float var = sq[t] * inv_n - m * m;
        float sc = g[t] * rsqrtf(var + EPS);
        float sh = be[t] - m * sc;
        ssc[t] = sc; ssh[t] = sh;
        scsh_out[t] = sc; scsh_out[HD + t] = sh;
    }
    __syncthreads();
    if (t < HD * HD) Wp[t] = ssc[t / HD] * W[t];
    if (t < HD) {
        float acc = 0.0f;
        #pragma unroll
        for (int k = 0; k < HD; ++k) acc = fmaf(ssh[k], W[k * HD + t], acc);
        cvec[t] = acc;
    }
    if (t < 600) {
        int k = t / 10;
        float s = (k < HD) ? scsh1[k] : (k < 2 * HD) ? ssc[k - HD] : 1.0f;
        Wlp[t] = s * Wl[t];
    }
    if (t < 10) {
        float acc = bl[t];
        #pragma unroll
        for (int k = 0; k < HD; ++k) acc = fmaf(scsh1[HD + k], Wl[k * 10 + t], acc);
        #pragma unroll
        for (int k = 0; k < HD; ++k) acc = fmaf(ssh[k], Wl[(HD + k) * 10 + t], acc);
        blp[t] = acc;
    }
}

extern "C" void kernel_launch(void* const* d_in, const int* in_sizes, int n_in,
                              void* d_out, int out_size, void* d_ws, size_t ws_size,
                              hipStream_t stream) {
    const float* x   = (const float*)d_in[0];
    const int*   ei  = (const int*)d_in[1];
    const float* ew  = (const float*)d_in[2];
    const float* W1  = (const float*)d_in[3];
    const float* b1  = (const float*)d_in[4];
    const float* g1  = (const float*)d_in[5];
    const float* be1 = (const float*)d_in[6];
    const float* W2  = (const float*)d_in[7];
    const float* b2  = (const float*)d_in[8];
    const float* g2  = (const float*)d_in[9];
    const float* be2 = (const float*)d_in[10];
    const float* W3  = (const float*)d_in[11];
    const float* b3  = (const float*)d_in[12];
    const float* Wl  = (const float*)d_in[13];
    const float* bl  = (const float*)d_in[14];
    float* out = (float*)d_out;

    const int F = in_sizes[3] / HD;       // 128
    const int N = in_sizes[0] / F;        // 100000
    const int E = in_sizes[2];            // 3200000
    const int* src = ei;
    const int* dst = ei + E;
    const int nbv = (N + 127) >> BSH;     // 782 buckets

    char* p = (char*)d_ws;
    auto alloc = [&](size_t bytes) -> void* {
        void* r = (void*)p;
        p += (bytes + 255) & ~(size_t)255;
        return r;
    };
    size_t nh4 = (size_t)N * HD * 4;                         // 8e6 B
    int2*  se      = (int2*) alloc((size_t)E * 8);           // CSR payload (src, ew)
    char*  regionA = (char*) alloc((size_t)E * 8);           // tmp -> hs|_|o1r
    float* o2r     = (float*)alloc(nh4);
    float* dinv    = (float*)alloc((size_t)N * 4);
    int*   row_start = (int*)alloc((size_t)(N + 1) * 4);
    int*   bcnt    = (int*)  alloc(NBMAX * 4);
    int*   bstart  = (int*)  alloc((NBMAX + 1) * 4);
    int*   bcur    = (int*)  alloc(NBMAX * 4);
    float* stats   = (float*)alloc(80 * 4);   // sum1,sq1,sum2,sq2
    float* scsh    = (float*)alloc(80 * 4);   // sc1,sh1,sc2,sh2
    float* zero20  = (float*)alloc(20 * 4);
    float* W2p     = (float*)alloc(400 * 4);
    float* c2      = (float*)alloc(20 * 4);
    float* W3p     = (float*)alloc(400 * 4);
    float* c3      = (float*)alloc(20 * 4);
    float* Wlp     = (float*)alloc(600 * 4);
    float* blp     = (float*)alloc(12 * 4);

    int2*   tmp = (int2*)regionA;
    __half* hs  = (__half*)regionA;                 // 6.4 MB fp16 (64B rows)
    float*  o1r = (float*)(regionA + 2 * nh4);      // at 16 MB (tmp is 25.6 MB)

    const int B = 256;
    const int GB = 512;                          // blocks for hist/scatter
    const int chunk = (E + GB - 1) / GB;         // 6250
    int gAgg = (4 * N + B - 1) / B;              // 1563 (4 lanes/node, 64 nodes/block)

    // ---- graph build (shared by all 3 layers) ----
    hipLaunchKernelGGL(init_kernel, dim3(1), dim3(1024), 0, stream, bcnt, stats, zero20, nbv);
    hipLaunchKernelGGL(bucket_hist_kernel, dim3(GB), dim3(B), 0, stream, dst, bcnt, E, chunk, nbv);
    hipLaunchKernelGGL(bucket_scan_kernel, dim3(1), dim3(1024), 0, stream,
                       bcnt, bstart, bcur, row_start, N, E, nbv);
    hipLaunchKernelGGL(scatter_kernel, dim3(GB), dim3(B), 0, stream,
                       src, dst, ew, bcur, tmp, E, chunk, nbv);
    hipLaunchKernelGGL(finalize_kernel, dim3(nbv), dim3(B), 0, stream,
                       tmp, bstart, se, row_start, dinv, N);

    // ---- layer 1 (no upstream BN: cvec = 0, bias = b1) ----
    hipLaunchKernelGGL((gemm_kernel<128, 16>), dim3((N + 15) / 16), dim3(B), 0, stream,
                       x, W1, zero20, dinv, hs, N);
    hipLaunchKernelGGL((agg_kernel<0>), dim3(gAgg), dim3(B), 0, stream,
                       hs, dinv, row_start, se, b1, o1r,
                       stats, stats + 20, nullptr, nullptr, nullptr, nullptr, N);
    hipLaunchKernelGGL(bn_adjust_kernel, dim3(1), dim3(512), 0, stream,
                       stats, stats + 20, g1, be1, W2, scsh, W2p, c2, N);

    // ---- layer 2 (BN1 scale in W2p, shift in c2 pre-agg; bias = raw b2) ----
    hipLaunchKernelGGL((gemm_kernel<HD, 64>), dim3((N + 63) / 64), dim3(B), 0, stream,
                       o1r, W2p, c2, dinv, hs, N);
    hipLaunchKernelGGL((agg_kernel<0>), dim3(gAgg), dim3(B), 0, stream,
                       hs, dinv, row_start, se, b2, o2r,
                       stats + 40, stats + 60, nullptr, nullptr, nullptr, nullptr, N);
    hipLaunchKernelGGL(bn_adjust2_kernel, dim3(1), dim3(640), 0, stream,
                       stats + 40, stats + 60, g2, be2, W3, scsh + 40, W3p, c3,
                       Wl, bl, scsh, Wlp, blp, N);

    // ---- layer 3 + fused final linear (writes d_out directly) ----
    hipLaunchKernelGGL((gemm_kernel<HD, 64>), dim3((N + 63) / 64), dim3(B), 0, stream,
                       o2r, W3p, c3, dinv, hs, N);
    hipLaunchKernelGGL((agg_kernel<1>), dim3(gAgg), dim3(B), 0, stream,
                       hs, dinv, row_start, se, b3, out,
                       nullptr, nullptr, o1r, o2r, Wlp, blp, N);
}